// Round 4
// baseline (78.218 us; speedup 1.0000x reference)
//
#include <hip/hip_runtime.h>
#include <math.h>

// ---------------------------------------------------------------------------
// RegressionLoss, R7: ONE launch. 256 blocks (1/CU), zero LDS in hot paths,
// R5's proven ticket protocol (relaxed agent sc1 atomics + vmcnt(0) drain),
// R6's packed-FMA chamfer math + explicit A/B double-buffered uniform
// float4 prefetch of the inner shape (hide load latency under compute --
// the suspected reason R6's scalar-load loop didn't beat R3).
//
// Cost model (all rounds reconciled): fill poison 40 us (unconditional,
// untouchable) + ~10 us fixed per-iteration overhead + ~10 us PER EXTRA
// dispatch. R7 removes the second dispatch and keeps the kernel ~5-8 us:
//   blocks 0..247   : 4 chamfer waves each (1 directional pair per wave)
//   blocks 248..255 : 4 dot-row waves each (1 row i per wave, row in regs)
//   ticket          : 256 agent-scope RMWs; 256th block runs the finish.
// ---------------------------------------------------------------------------

typedef float f32x2 __attribute__((ext_vector_type(2)));

__device__ float g_cdHalf[992];          // directional chamfer halves
__device__ float g_dots[1024];           // 32x32 normalized inner products
__device__ unsigned int g_counter = 0;   // monotone; ticket = old & 255

__device__ __forceinline__ float waveReduceSum64(float v) {
    #pragma unroll
    for (int m = 32; m > 0; m >>= 1) v += __shfl_xor(v, m, 64);
    return v;
}

__global__ __launch_bounds__(256) void fused_kernel(const float* __restrict__ emb,
                                                    const float* __restrict__ xyz,
                                                    float* __restrict__ out) {
    const int t = threadIdx.x;
    const int b = blockIdx.x;
    const int w    = t >> 6;
    const int lane = t & 63;

    __shared__ float red[4];
    __shared__ unsigned int ticket;

    if (b < 248) {
        // ---- one directional chamfer pair per wave ----
        const int pairIdx = __builtin_amdgcn_readfirstlane((b << 2) | w);  // 0..991
        const int pb  = pairIdx >> 1;
        const int dir = pairIdx & 1;
        int ii = 0, rem = pb;                       // strict upper-tri decode
        while (rem >= (31 - ii)) { rem -= (31 - ii); ++ii; }
        const int jj = ii + 1 + rem;
        const int outer = dir ? jj : ii;
        const int inner = dir ? ii : jj;

        const float*  Po = xyz + (32 + outer) * 768;                 // shapes = xyz[32:]
        const float4* Q4 = (const float4*)(xyz + (32 + inner) * 768); // 192 float4, uniform

        // 4 outer points per lane: lane, lane+64, lane+128, lane+192
        float px[4], py[4], pz[4], pp[4];
        #pragma unroll
        for (int k = 0; k < 4; ++k) {
            const float* P = Po + 3 * (lane + 64 * k);
            px[k] = P[0]; py[k] = P[1]; pz[k] = P[2];
            pp[k] = px[k] * px[k] + py[k] * py[k] + pz[k] * pz[k];
        }
        // fold -2 into the outer coords: e = |q|^2 + X*qx + Y*qy + Z*qz
        const f32x2 X01 = {-2.f * px[0], -2.f * px[1]}, X23 = {-2.f * px[2], -2.f * px[3]};
        const f32x2 Y01 = {-2.f * py[0], -2.f * py[1]}, Y23 = {-2.f * py[2], -2.f * py[3]};
        const f32x2 Z01 = {-2.f * pz[0], -2.f * pz[1]}, Z23 = {-2.f * pz[2], -2.f * pz[3]};

        f32x2 m01 = {3.4e38f, 3.4e38f}, m23 = {3.4e38f, 3.4e38f};

#define CHAM_PT(QX_, QY_, QZ_) do {                                   \
            const float qx_ = (QX_), qy_ = (QY_), qz_ = (QZ_);        \
            const float qw_ = qx_*qx_ + qy_*qy_ + qz_*qz_;            \
            f32x2 e01 = {qw_, qw_}, e23 = {qw_, qw_};                 \
            e01 = Z01 * (f32x2){qz_, qz_} + e01;                      \
            e01 = Y01 * (f32x2){qy_, qy_} + e01;                      \
            e01 = X01 * (f32x2){qx_, qx_} + e01;                      \
            e23 = Z23 * (f32x2){qz_, qz_} + e23;                      \
            e23 = Y23 * (f32x2){qy_, qy_} + e23;                      \
            e23 = X23 * (f32x2){qx_, qx_} + e23;                      \
            m01.x = fminf(m01.x, e01.x); m01.y = fminf(m01.y, e01.y); \
            m23.x = fminf(m23.x, e23.x); m23.y = fminf(m23.y, e23.y); \
        } while (0)

#define LOADG(A0,A1,A2,A3,A4,A5, gidx) do {                           \
            const float4* qp_ = Q4 + 6 * (gidx);                      \
            A0 = qp_[0]; A1 = qp_[1]; A2 = qp_[2];                    \
            A3 = qp_[3]; A4 = qp_[4]; A5 = qp_[5];                    \
        } while (0)

#define COMPG(A0,A1,A2,A3,A4,A5) do {                                 \
            CHAM_PT(A0.x, A0.y, A0.z);                                \
            CHAM_PT(A0.w, A1.x, A1.y);                                \
            CHAM_PT(A1.z, A1.w, A2.x);                                \
            CHAM_PT(A2.y, A2.z, A2.w);                                \
            CHAM_PT(A3.x, A3.y, A3.z);                                \
            CHAM_PT(A3.w, A4.x, A4.y);                                \
            CHAM_PT(A4.z, A4.w, A5.x);                                \
            CHAM_PT(A5.y, A5.z, A5.w);                                \
        } while (0)

        // A/B double-buffered stream over 32 groups of 8 inner points
        float4 a0,a1,a2,a3,a4,a5, c0,c1,c2,c3,c4,c5;
        LOADG(a0,a1,a2,a3,a4,a5, 0);
        for (int g = 0; g < 32; g += 2) {
            LOADG(c0,c1,c2,c3,c4,c5, g + 1);       // prefetch odd group
            COMPG(a0,a1,a2,a3,a4,a5);
            if (g + 2 < 32) LOADG(a0,a1,a2,a3,a4,a5, g + 2);  // prefetch next even
            COMPG(c0,c1,c2,c3,c4,c5);
        }
#undef COMPG
#undef LOADG
#undef CHAM_PT

        float ssum = (m01.x + pp[0]) + (m01.y + pp[1]) +
                     (m23.x + pp[2]) + (m23.y + pp[3]);
        ssum = waveReduceSum64(ssum);
        if (lane == 0)
            __hip_atomic_store(&g_cdHalf[pairIdx], ssum * (1.0f / 256.0f),
                               __ATOMIC_RELAXED, __HIP_MEMORY_SCOPE_AGENT);
    } else {
        // ---- one dot row per wave: dots[i*32+j] = cos(emb_i, emb_{32+j}) ----
        const int i = ((b - 248) << 2) | w;        // row 0..31
        const float* Ei = emb + i * 512;
        float ai[8];
        #pragma unroll
        for (int m = 0; m < 8; ++m) ai[m] = Ei[lane + 64 * m];
        float ni = 0.0f;
        #pragma unroll
        for (int m = 0; m < 8; ++m) ni += ai[m] * ai[m];
        ni = waveReduceSum64(ni);

        for (int j = 0; j < 32; ++j) {
            const float* Ej = emb + (32 + j) * 512;
            float dot = 0.0f, nj = 0.0f;
            #pragma unroll
            for (int m = 0; m < 8; ++m) {
                const float bv = Ej[lane + 64 * m];
                dot += ai[m] * bv;
                nj  += bv * bv;
            }
            dot = waveReduceSum64(dot);
            nj  = waveReduceSum64(nj);
            if (lane == 0)
                __hip_atomic_store(&g_dots[i * 32 + j], dot * rsqrtf(ni * nj),
                                   __ATOMIC_RELAXED, __HIP_MEMORY_SCOPE_AGENT);
        }
    }

    // ---- completion ticket (R5-proven protocol, 256 blocks) ----
    asm volatile("s_waitcnt vmcnt(0)" ::: "memory");
    __syncthreads();
    if (t == 0)
        ticket = __hip_atomic_fetch_add(&g_counter, 1u, __ATOMIC_RELAXED,
                                        __HIP_MEMORY_SCOPE_AGENT) & 255u;
    __syncthreads();
    if (ticket != 255u) return;

    // ---- finish (last block only): 256 threads, 4 (i,j) entries each ----
    const int fi = t >> 3;                      // row 0..31
    const int jb = (t & 7) << 2;                // col base
    const float inv_denom = 1.0f / (2.0f * (0.997f / 3.0f) * (0.997f / 3.0f));

    float sv[4], hv[4];
    #pragma unroll
    for (int k = 0; k < 4; ++k) {
        const int j = jb + k;
        float c = 0.0f;                         // chamfer(self) == 0
        if (fi != j) {
            const int a  = fi < j ? fi : j;
            const int bb = fi < j ? j : fi;
            const int pq = a * 31 - (a * (a - 1)) / 2 + (bb - a - 1);
            const float c0 = __hip_atomic_load(&g_cdHalf[2*pq],     __ATOMIC_RELAXED, __HIP_MEMORY_SCOPE_AGENT);
            const float c1 = __hip_atomic_load(&g_cdHalf[2*pq + 1], __ATOMIC_RELAXED, __HIP_MEMORY_SCOPE_AGENT);
            c = c0 + c1;
        }
        sv[k] = -(c * c) * inv_denom;
        hv[k] = __hip_atomic_load(&g_dots[fi * 32 + jb + k], __ATOMIC_RELAXED, __HIP_MEMORY_SCOPE_AGENT);
    }

    // row softmaxes: 8 lanes per row, xor 1,2,4 stays within the row group
    float mx1 = fmaxf(fmaxf(sv[0], sv[1]), fmaxf(sv[2], sv[3]));
    float mx2 = fmaxf(fmaxf(hv[0], hv[1]), fmaxf(hv[2], hv[3]));
    #pragma unroll
    for (int m = 1; m <= 4; m <<= 1) {
        mx1 = fmaxf(mx1, __shfl_xor(mx1, m, 64));
        mx2 = fmaxf(mx2, __shfl_xor(mx2, m, 64));
    }
    float e1[4], e2[4], sum1 = 0.0f, sum2 = 0.0f;
    #pragma unroll
    for (int k = 0; k < 4; ++k) {
        e1[k] = expf(sv[k] - mx1); sum1 += e1[k];
        e2[k] = expf(hv[k] - mx2); sum2 += e2[k];
    }
    #pragma unroll
    for (int m = 1; m <= 4; m <<= 1) {
        sum1 += __shfl_xor(sum1, m, 64);
        sum2 += __shfl_xor(sum2, m, 64);
    }
    float acc = 0.0f;
    #pragma unroll
    for (int k = 0; k < 4; ++k) acc += fabsf(e2[k] / sum2 - e1[k] / sum1);

    acc = waveReduceSum64(acc);
    if ((t & 63) == 0) red[t >> 6] = acc;
    __syncthreads();
    if (t == 0)
        out[0] = (red[0] + red[1] + red[2] + red[3]) * (1.0f / 1024.0f);
}

extern "C" void kernel_launch(void* const* d_in, const int* in_sizes, int n_in,
                              void* d_out, int out_size, void* d_ws, size_t ws_size,
                              hipStream_t stream) {
    (void)in_sizes; (void)n_in; (void)out_size; (void)d_ws; (void)ws_size;
    const float* emb = (const float*)d_in[0];   // 64 x 512
    const float* xyz = (const float*)d_in[1];   // 64 x 256 x 3
    float* out = (float*)d_out;

    hipLaunchKernelGGL(fused_kernel, dim3(256), dim3(256), 0, stream, emb, xyz, out);
}

// Round 5
// 66.898 us; speedup vs baseline: 1.1692x; 1.1692x over previous
//
#include <hip/hip_runtime.h>
#include <math.h>

// ---------------------------------------------------------------------------
// RegressionLoss, R8: two launches (proven fastest structure), SGPR-broadcast
// chamfer (zero LDS in the hot loop).
//
// Session facts: 256 MiB poison fill ~40 us unconditional; single-launch
// ticket designs 3-for-3 slower (75/78/136 us vs 66.5); R3's pairs kernel is
// LDS-return-bus bound (~15 us: 192 ds_read_b128/wave broadcast of the
// inner shape); VALU floor of the chamfer is ~2-4 us.
//
// R8 pairs kernel, chamfer block (1 directional pair, 4 waves):
//   - each wave: ALL 256 outer points (4/lane, f32x2-packed, -2 folded) x
//     a 64-point inner quarter (1 inner point/lane in registers)
//   - inner point broadcast lane->SGPR via v_readlane (immediate lane id,
//     unrolled 64x) consumed as the scalar operand of v_pk_fma_f32
//   - per-wave partial mins (+|p|^2, legal since +pp is monotone wrt min)
//     merged via a 4 KB LDS pass, then block sum -> cdHalf[pair].
// Grid 1024 = 992 chamfer + 32 dot rows (R3's balanced 4 blocks/CU).
// Dot-row blocks and finish kernel: unchanged from R3 (verified).
// ---------------------------------------------------------------------------

typedef float f32x2 __attribute__((ext_vector_type(2)));

__device__ __forceinline__ float waveReduceSum64(float v) {
    #pragma unroll
    for (int m = 32; m > 0; m >>= 1) v += __shfl_xor(v, m, 64);
    return v;
}

__device__ __forceinline__ float readlane_f(float v, int l) {
    return __int_as_float(__builtin_amdgcn_readlane(__float_as_int(v), l));
}

// blocks [0,992): directional chamfer half b -> cdHalf[b]
// blocks [992,1024): dot row i=b-992 -> dots[i*32+j]
__global__ __launch_bounds__(256) void pairs_kernel(const float* __restrict__ emb,
                                                    const float* __restrict__ xyz,
                                                    float* __restrict__ cdHalf,
                                                    float* __restrict__ dots) {
    const int t = threadIdx.x;
    const int b = blockIdx.x;
    const int w    = t >> 6;
    const int lane = t & 63;

    __shared__ __align__(16) float M[1024];   // per-wave partial mins (+pp)
    __shared__ float red[4];

    if (b < 992) {
        const int pb  = b >> 1;
        const int dir = b & 1;
        int ii = 0, rem = pb;                      // strict upper-tri decode
        while (rem >= (31 - ii)) { rem -= (31 - ii); ++ii; }
        const int jj = ii + 1 + rem;
        const int outer = dir ? jj : ii;
        const int inner = dir ? ii : jj;

        const float* Po = xyz + (32 + outer) * 768;   // shapes = xyz[32:]
        const float* Pi = xyz + (32 + inner) * 768;

        // my inner point (this wave's quarter): 1 per lane, in registers
        const float* Q = Pi + 3 * (64 * w + lane);
        const float qx = Q[0], qy = Q[1], qz = Q[2];
        const float qw = qx * qx + qy * qy + qz * qz;

        // 4 outer points per lane: 64k + lane
        float px[4], py[4], pz[4], pp[4];
        #pragma unroll
        for (int k = 0; k < 4; ++k) {
            const float* P = Po + 3 * (64 * k + lane);
            px[k] = P[0]; py[k] = P[1]; pz[k] = P[2];
            pp[k] = px[k] * px[k] + py[k] * py[k] + pz[k] * pz[k];
        }
        // fold -2 into outer coords: e = |q|^2 + X*qx + Y*qy + Z*qz
        const f32x2 X01 = {-2.f * px[0], -2.f * px[1]}, X23 = {-2.f * px[2], -2.f * px[3]};
        const f32x2 Y01 = {-2.f * py[0], -2.f * py[1]}, Y23 = {-2.f * py[2], -2.f * py[3]};
        const f32x2 Z01 = {-2.f * pz[0], -2.f * pz[1]}, Z23 = {-2.f * pz[2], -2.f * pz[3]};

        f32x2 m01 = {3.4e38f, 3.4e38f}, m23 = {3.4e38f, 3.4e38f};

        // 64 inner points of this wave's quarter, broadcast lane -> SGPR
        #pragma unroll
        for (int k = 0; k < 64; ++k) {
            const float sx = readlane_f(qx, k);
            const float sy = readlane_f(qy, k);
            const float sz = readlane_f(qz, k);
            const float sw = readlane_f(qw, k);
            const f32x2 SW = {sw, sw};
            f32x2 e01 = Z01 * (f32x2){sz, sz} + SW;
            e01 = Y01 * (f32x2){sy, sy} + e01;
            e01 = X01 * (f32x2){sx, sx} + e01;
            f32x2 e23 = Z23 * (f32x2){sz, sz} + SW;
            e23 = Y23 * (f32x2){sy, sy} + e23;
            e23 = X23 * (f32x2){sx, sx} + e23;
            m01.x = fminf(m01.x, e01.x); m01.y = fminf(m01.y, e01.y);
            m23.x = fminf(m23.x, e23.x); m23.y = fminf(m23.y, e23.y);
        }

        // partial mins (+pp) to LDS: M[w][k][lane], outer point = 64k+lane
        M[w * 256 +   0 + lane] = m01.x + pp[0];
        M[w * 256 +  64 + lane] = m01.y + pp[1];
        M[w * 256 + 128 + lane] = m23.x + pp[2];
        M[w * 256 + 192 + lane] = m23.y + pp[3];
        __syncthreads();

        // thread t owns outer point t: min over the 4 inner quarters
        const float v = fminf(fminf(M[t], M[256 + t]),
                              fminf(M[512 + t], M[768 + t]));
        float s = waveReduceSum64(v);
        if (lane == 0) red[w] = s;
        __syncthreads();
        if (t == 0)
            cdHalf[b] = (red[0] + red[1] + red[2] + red[3]) * (1.0f / 256.0f);
    } else {
        // ---- dot row i: dots[i*32+j] = cos(emb_i, emb_{32+j}) ----
        const int i = b - 992;
        float* rowi = M;                       // 512 floats
        const float* Ei = emb + i * 512;
        rowi[t]       = Ei[t];
        rowi[t + 256] = Ei[t + 256];
        __syncthreads();

        float ni = 0.0f;
        #pragma unroll
        for (int m = 0; m < 8; ++m) { float a = rowi[lane + 64 * m]; ni += a * a; }
        ni = waveReduceSum64(ni);

        for (int j = w; j < 32; j += 4) {
            const float* Ej = emb + (32 + j) * 512;
            float dot = 0.0f, nj = 0.0f;
            #pragma unroll
            for (int m = 0; m < 8; ++m) {
                float a  = rowi[lane + 64 * m];
                float bv = Ej[lane + 64 * m];
                dot += a * bv;
                nj  += bv * bv;
            }
            dot = waveReduceSum64(dot);
            nj  = waveReduceSum64(nj);
            if (lane == 0) dots[i * 32 + j] = dot * rsqrtf(ni * nj);
        }
    }
}

// 1 block x 1024 threads: assemble cd, softmaxes, mean abs diff (verified)
__global__ __launch_bounds__(1024) void finish_kernel(const float* __restrict__ cdHalf,
                                                      const float* __restrict__ dots,
                                                      float* __restrict__ out) {
    const int t = threadIdx.x;   // t = i*32 + j ; width-32 segments == rows
    const int i = t >> 5;
    const int j = t & 31;
    const float inv_denom = 1.0f / (2.0f * (0.997f / 3.0f) * (0.997f / 3.0f));

    float c;
    if (i == j) {
        c = 0.0f;                 // chamfer(self) == 0
    } else {
        const int a  = min(i, j), bb = max(i, j);
        const int pb = a * 31 - (a * (a - 1)) / 2 + (bb - a - 1);
        c = cdHalf[2 * pb] + cdHalf[2 * pb + 1];
    }
    float s = -(c * c) * inv_denom;
    float h = dots[t];

    float m1 = s;
    #pragma unroll
    for (int k = 16; k > 0; k >>= 1) m1 = fmaxf(m1, __shfl_xor(m1, k, 32));
    float e1 = expf(s - m1);
    float sum1 = e1;
    #pragma unroll
    for (int k = 16; k > 0; k >>= 1) sum1 += __shfl_xor(sum1, k, 32);
    float p = e1 / sum1;

    float m2 = h;
    #pragma unroll
    for (int k = 16; k > 0; k >>= 1) m2 = fmaxf(m2, __shfl_xor(m2, k, 32));
    float e2 = expf(h - m2);
    float sum2 = e2;
    #pragma unroll
    for (int k = 16; k > 0; k >>= 1) sum2 += __shfl_xor(sum2, k, 32);
    float ph = e2 / sum2;

    float a = fabsf(ph - p);
    a = waveReduceSum64(a);

    __shared__ float red[16];
    if ((t & 63) == 0) red[t >> 6] = a;
    __syncthreads();
    if (t == 0) {
        float tot = 0.0f;
        #pragma unroll
        for (int k = 0; k < 16; ++k) tot += red[k];
        out[0] = tot * (1.0f / 1024.0f);
    }
}

extern "C" void kernel_launch(void* const* d_in, const int* in_sizes, int n_in,
                              void* d_out, int out_size, void* d_ws, size_t ws_size,
                              hipStream_t stream) {
    (void)in_sizes; (void)n_in; (void)out_size; (void)ws_size;
    const float* emb = (const float*)d_in[0];   // 64 x 512
    const float* xyz = (const float*)d_in[1];   // 64 x 256 x 3
    float* cdHalf = (float*)d_ws;               // 992 directional halves
    float* dots   = cdHalf + 1024;              // 32x32
    float* out    = (float*)d_out;

    hipLaunchKernelGGL(pairs_kernel, dim3(1024), dim3(256), 0, stream, emb, xyz, cdHalf, dots);
    hipLaunchKernelGGL(finish_kernel, dim3(1), dim3(1024), 0, stream, cdHalf, dots, out);
}